// Round 10
// baseline (2126.334 us; speedup 1.0000x reference)
//
#include <hip/hip_runtime.h>
#include <stdint.h>

#define HID    2048
#define MPTS   16425
#define MTILES 129    // ceil(16425/128)
#define NTIL   16     // 2048/128
#define KTIL   64     // 2048/32
#define BIMG   5120   // shorts per packed padded B tile image (128 rows * 40)

typedef float f32x4  __attribute__((ext_vector_type(4)));
typedef short bf16x8 __attribute__((ext_vector_type(8)));
typedef short bf16x4 __attribute__((ext_vector_type(4)));

__device__ __forceinline__ float bf2f(unsigned short h) {
    unsigned u = ((unsigned)h) << 16;
    return __builtin_bit_cast(float, u);
}
__device__ __forceinline__ unsigned short f2bf(float f) {
    unsigned u = __builtin_bit_cast(unsigned, f);
    u = u + 0x7FFFu + ((u >> 16) & 1u);
    return (unsigned short)(u >> 16);
}

// ---------------------------------------------------------------------------
// Pack fp32 W (K x N row-major) into hi/lo bf16 padded tile images:
// img(L,nt,kt)[n*40+k] = W[kt*32+k][nt*128+n]; pad k=32..39 (zeros).
// Padded in GLOBAL so global_load_lds can copy it contiguously (m104 caveat).
// ---------------------------------------------------------------------------
__global__ void pack_w_hl(const float* __restrict__ w1,
                          const float* __restrict__ w2,
                          const float* __restrict__ w3,
                          unsigned short* __restrict__ wph,
                          unsigned short* __restrict__ wpl) {
    const int kt = blockIdx.x, nt = blockIdx.y, L = blockIdx.z;
    const float* W = (L == 0) ? w1 : ((L == 1) ? w2 : w3);
    __shared__ float tl[128 * 33];   // [n][k] transposed, padded
    const int tid = threadIdx.x;
    const int k  = tid >> 3;          // 0..31
    const int nc = (tid & 7) * 16;    // 0..112
    const float* src = W + (size_t)(kt * 32 + k) * HID + nt * 128 + nc;
    #pragma unroll
    for (int j = 0; j < 16; ++j) tl[(nc + j) * 33 + k] = src[j];
    __syncthreads();
    const size_t base = (size_t)(L * 1024 + nt * 64 + kt) * BIMG;
    for (int e = tid; e < BIMG; e += 256) {
        int n = e / 40, kk = e - n * 40;
        float a = (kk < 32) ? tl[n * 33 + kk] : 0.f;
        unsigned short hs = f2bf(a);
        wph[base + e] = hs;
        wpl[base + e] = f2bf(a - bf2f(hs));
    }
}

// ---------------------------------------------------------------------------
// Layer 0 (pair out): v=relu(xs*w0+b0); store bf16 hi/lo pair, row-major
// ---------------------------------------------------------------------------
__global__ void layer0p(const float* __restrict__ xs,
                        const float* __restrict__ w0,
                        const float* __restrict__ b0,
                        unsigned short* __restrict__ Ahg,
                        unsigned short* __restrict__ Alg, int row0) {
    const int r = blockIdx.x;
    const int grow = row0 + r;
    const int j = threadIdx.x * 8;
    const float x = (grow < MPTS) ? xs[grow] : 0.f;
    bf16x8 h, l;
    #pragma unroll
    for (int q = 0; q < 8; ++q) {
        float v = x * w0[j + q] + b0[j + q];
        v = v > 0.f ? v : 0.f;
        unsigned short hs = f2bf(v);
        h[q] = (short)hs;
        l[q] = (short)f2bf(v - bf2f(hs));
    }
    *(bf16x8*)(Ahg + (size_t)r * HID + j) = h;
    *(bf16x8*)(Alg + (size_t)r * HID + j) = l;
}

// ---------------------------------------------------------------------------
// MFMA GEMM v3: A fragments loaded DIRECTLY from global (16x16x32 A-operand
// layout == 16B contiguous in row-major), B via global_load_lds into a
// double-buffered LDS (one barrier per k-step, prefetch 1 step ahead).
// 128x128 tile, BK=32, 4 waves of 64x64, 3 MFMA per fragment pair.
// ---------------------------------------------------------------------------
__launch_bounds__(256, 3)
__global__ void gemm_hl(const unsigned short* __restrict__ Ahg,
                        const unsigned short* __restrict__ Alg,
                        const unsigned short* __restrict__ wph,
                        const unsigned short* __restrict__ wpl,
                        const float* __restrict__ bias,
                        unsigned short* __restrict__ Chg,
                        unsigned short* __restrict__ Clg, int layer) {
    __shared__ short Bh[2][BIMG];   // 2 x 10240 B
    __shared__ short Bl[2][BIMG];

    const int tid  = threadIdx.x;
    const int lane = tid & 63;
    const int wave = tid >> 6;
    const int quad = lane >> 4;
    const int lidx = lane & 15;
    const int nt = blockIdx.x;
    const int m0 = blockIdx.y * 128;    // chunk-local
    const int mbase = (wave >> 1) * 64;
    const int nbase = (wave & 1) * 64;

    const size_t wbase = (size_t)(layer * 1024 + nt * 64) * BIMG;
    const char* gH = (const char*)(wph + wbase);
    const char* gL = (const char*)(wpl + wbase);

    // A-fragment row base (16B loads at row*HID + kt*32 + quad*8)
    const unsigned short* aH = Ahg + (size_t)(m0 + mbase + lidx) * HID;
    const unsigned short* aL = Alg + (size_t)(m0 + mbase + lidx) * HID;

    f32x4 acc[4][4];
    #pragma unroll
    for (int i = 0; i < 4; ++i)
        #pragma unroll
        for (int j = 0; j < 4; ++j) acc[i][j] = (f32x4)0.f;

    // prologue: stage kt=0 into buffer 0 (async global->LDS)
    for (int t = wave; t < 10; t += 4) {
        __builtin_amdgcn_global_load_lds(
            (const __attribute__((address_space(1))) unsigned int*)(gH + t * 1024 + lane * 16),
            (__attribute__((address_space(3))) unsigned int*)((char*)&Bh[0][0] + t * 1024),
            16, 0, 0);
        __builtin_amdgcn_global_load_lds(
            (const __attribute__((address_space(1))) unsigned int*)(gL + t * 1024 + lane * 16),
            (__attribute__((address_space(3))) unsigned int*)((char*)&Bl[0][0] + t * 1024),
            16, 0, 0);
    }
    __syncthreads();   // drain prologue staging

    for (int kt = 0; kt < KTIL; ++kt) {
        const int buf = kt & 1;

        // ---- prefetch next B tile into the other buffer (in-flight across MFMA)
        if (kt + 1 < KTIL) {
            const char* nH = gH + (size_t)(kt + 1) * (BIMG * 2);
            const char* nL = gL + (size_t)(kt + 1) * (BIMG * 2);
            char* dH = (char*)&Bh[buf ^ 1][0];
            char* dL = (char*)&Bl[buf ^ 1][0];
            for (int t = wave; t < 10; t += 4) {
                __builtin_amdgcn_global_load_lds(
                    (const __attribute__((address_space(1))) unsigned int*)(nH + t * 1024 + lane * 16),
                    (__attribute__((address_space(3))) unsigned int*)(dH + t * 1024),
                    16, 0, 0);
                __builtin_amdgcn_global_load_lds(
                    (const __attribute__((address_space(1))) unsigned int*)(nL + t * 1024 + lane * 16),
                    (__attribute__((address_space(3))) unsigned int*)(dL + t * 1024),
                    16, 0, 0);
            }
        }

        // ---- A fragments direct from global (L2/L3-resident) ----
        const int ko = kt * 32 + quad * 8;
        bf16x8 afh[4], afl[4];
        #pragma unroll
        for (int mm = 0; mm < 4; ++mm) {
            afh[mm] = *(const bf16x8*)(aH + (size_t)(mm * 16) * HID + ko);
            afl[mm] = *(const bf16x8*)(aL + (size_t)(mm * 16) * HID + ko);
        }

        // ---- B fragments from LDS (current buffer) ----
        bf16x8 bfh[4], bfl[4];
        #pragma unroll
        for (int nn = 0; nn < 4; ++nn) {
            int r = nbase + nn * 16 + lidx;
            bfh[nn] = *(const bf16x8*)(&Bh[buf][r * 40 + quad * 8]);
            bfl[nn] = *(const bf16x8*)(&Bl[buf][r * 40 + quad * 8]);
        }

        #pragma unroll
        for (int mm = 0; mm < 4; ++mm)
            #pragma unroll
            for (int nn = 0; nn < 4; ++nn) {
                acc[mm][nn] = __builtin_amdgcn_mfma_f32_16x16x32_bf16(afh[mm], bfh[nn], acc[mm][nn], 0, 0, 0);
                acc[mm][nn] = __builtin_amdgcn_mfma_f32_16x16x32_bf16(afl[mm], bfh[nn], acc[mm][nn], 0, 0, 0);
                acc[mm][nn] = __builtin_amdgcn_mfma_f32_16x16x32_bf16(afh[mm], bfl[nn], acc[mm][nn], 0, 0, 0);
            }

        __syncthreads();   // reads of buf done; prefetch into buf^1 drained
    }

    // epilogue: C/D layout col=lane&15, row=quad*4+reg; write hi/lo pair
    #pragma unroll
    for (int nn = 0; nn < 4; ++nn) {
        const int col = nt * 128 + nbase + nn * 16 + lidx;
        const float bv = bias[col];
        #pragma unroll
        for (int mm = 0; mm < 4; ++mm) {
            const int mrow = m0 + mbase + mm * 16 + quad * 4;
            #pragma unroll
            for (int r = 0; r < 4; ++r) {
                float v = acc[mm][nn][r] + bv;
                v = v > 0.f ? v : 0.f;
                unsigned short hs = f2bf(v);
                Chg[(size_t)(mrow + r) * HID + col] = hs;
                Clg[(size_t)(mrow + r) * HID + col] = f2bf(v - bf2f(hs));
            }
        }
    }
}

// ---------------------------------------------------------------------------
// Layer 4 (pair in): Amg = relu(dot(Ah+Al, w4) + b4); one wave per row
// ---------------------------------------------------------------------------
__global__ void layer4p(const unsigned short* __restrict__ Ahg,
                        const unsigned short* __restrict__ Alg,
                        const float* __restrict__ w4,
                        const float* __restrict__ b4,
                        float* __restrict__ Amg, int row0) {
    const int lane = threadIdx.x & 63;
    const int wave = threadIdx.x >> 6;
    const int r    = blockIdx.x * 4 + wave;
    if (row0 + r >= MPTS) return;
    const unsigned short* ah = Ahg + (size_t)r * HID;
    const unsigned short* al = Alg + (size_t)r * HID;
    float s = 0.f;
    #pragma unroll
    for (int c = 0; c < 8; ++c) {
        const int col = c * 256 + lane * 4;
        bf16x4 hv = *(const bf16x4*)(ah + col);
        bf16x4 lv = *(const bf16x4*)(al + col);
        f32x4 wv = *(const f32x4*)(w4 + col);
        #pragma unroll
        for (int q = 0; q < 4; ++q)
            s += (bf2f((unsigned short)hv[q]) + bf2f((unsigned short)lv[q])) * wv[q];
    }
    #pragma unroll
    for (int off = 32; off; off >>= 1) s += __shfl_down(s, off);
    if (lane == 0) {
        float v = s + b4[0];
        Amg[row0 + r] = v > 0.f ? v : 0.f;
    }
}

// ---------------------------------------------------------------------------
// Fallback fp32 path (ws too small for packed images)
// ---------------------------------------------------------------------------
__global__ void layer0f(const float* __restrict__ xs, const float* __restrict__ w0,
                        const float* __restrict__ b0, float* __restrict__ A, int row0) {
    const int r = blockIdx.x;
    const int j = threadIdx.x * 8;
    const float x = (row0 + r < MPTS) ? xs[row0 + r] : 0.f;
    float* out = A + (size_t)r * HID + j;
    #pragma unroll
    for (int q = 0; q < 8; ++q) {
        float v = x * w0[j + q] + b0[j + q];
        out[q] = v > 0.f ? v : 0.f;
    }
}

__launch_bounds__(256)
__global__ void gemm_valu(const float* __restrict__ A, const float* __restrict__ W,
                          const float* __restrict__ bias, float* __restrict__ C) {
    __shared__ float As[16][132];
    __shared__ float Ws[16][132];
    const int tid = threadIdx.x;
    const int tx = tid & 15, ty = tid >> 4;
    const int n0 = blockIdx.x * 128;
    const int m0 = blockIdx.y * 128;
    const int am = tid & 127, ak = (tid >> 7) * 8;
    const int wn = (tid & 15) * 8, wk = tid >> 4;
    const float* aptr = A + (size_t)(m0 + am) * HID + ak;
    const float* wptr = W + (size_t)wk * HID + n0 + wn;
    float acc[8][8];
    #pragma unroll
    for (int i = 0; i < 8; ++i)
        #pragma unroll
        for (int j = 0; j < 8; ++j) acc[i][j] = 0.f;
    for (int k0 = 0; k0 < HID; k0 += 16) {
        f32x4 a0 = *(const f32x4*)(aptr + k0);
        f32x4 a1 = *(const f32x4*)(aptr + k0 + 4);
        f32x4 w0v = *(const f32x4*)(wptr + (size_t)k0 * HID);
        f32x4 w1v = *(const f32x4*)(wptr + (size_t)k0 * HID + 4);
        __syncthreads();
        As[ak + 0][am] = a0[0]; As[ak + 1][am] = a0[1];
        As[ak + 2][am] = a0[2]; As[ak + 3][am] = a0[3];
        As[ak + 4][am] = a1[0]; As[ak + 5][am] = a1[1];
        As[ak + 6][am] = a1[2]; As[ak + 7][am] = a1[3];
        *(f32x4*)&Ws[wk][wn]     = w0v;
        *(f32x4*)&Ws[wk][wn + 4] = w1v;
        __syncthreads();
        #pragma unroll
        for (int kk = 0; kk < 16; ++kk) {
            f32x4 av0 = *(const f32x4*)&As[kk][ty * 8];
            f32x4 av1 = *(const f32x4*)&As[kk][ty * 8 + 4];
            f32x4 bv0 = *(const f32x4*)&Ws[kk][tx * 8];
            f32x4 bv1 = *(const f32x4*)&Ws[kk][tx * 8 + 4];
            float a[8] = {av0[0], av0[1], av0[2], av0[3], av1[0], av1[1], av1[2], av1[3]};
            float b[8] = {bv0[0], bv0[1], bv0[2], bv0[3], bv1[0], bv1[1], bv1[2], bv1[3]};
            #pragma unroll
            for (int i = 0; i < 8; ++i)
                #pragma unroll
                for (int j = 0; j < 8; ++j) acc[i][j] += a[i] * b[j];
        }
    }
    #pragma unroll
    for (int i = 0; i < 8; ++i) {
        const int m = m0 + ty * 8 + i;
        #pragma unroll
        for (int jc = 0; jc < 2; ++jc) {
            const int n = n0 + tx * 8 + jc * 4;
            f32x4 v4;
            #pragma unroll
            for (int q = 0; q < 4; ++q) {
                float v = acc[i][jc * 4 + q] + bias[n + q];
                v4[q] = v > 0.f ? v : 0.f;
            }
            *(f32x4*)(C + (size_t)m * HID + n) = v4;
        }
    }
}

__global__ void layer4f(const float* __restrict__ A, const float* __restrict__ w4,
                        const float* __restrict__ b4, float* __restrict__ Amg, int row0) {
    const int lane = threadIdx.x & 63;
    const int wave = threadIdx.x >> 6;
    const int r    = blockIdx.x * 4 + wave;
    if (row0 + r >= MPTS) return;
    const float* ap = A + (size_t)r * HID;
    float s = 0.f;
    #pragma unroll
    for (int c = 0; c < 8; ++c) {
        const int col = c * 256 + lane * 4;
        f32x4 av = *(const f32x4*)(ap + col);
        f32x4 wv = *(const f32x4*)(w4 + col);
        s += av[0] * wv[0] + av[1] * wv[1] + av[2] * wv[2] + av[3] * wv[3];
    }
    #pragma unroll
    for (int off = 32; off; off >>= 1) s += __shfl_down(s, off);
    if (lane == 0) {
        float v = s + b4[0];
        Amg[row0 + r] = v > 0.f ? v : 0.f;
    }
}

// ---------------------------------------------------------------------------
// Multigrid level: interp (2n-1) + band overwrite; all fp32 (d_out is fp32).
// ---------------------------------------------------------------------------
__global__ void mg_level(const float* __restrict__ in, float* __restrict__ outf,
                         const int* __restrict__ nbrs_base, int level,
                         const float* __restrict__ band, int n_out) {
    const int j = blockIdx.x * 256 + threadIdx.x;
    if (j >= n_out) return;
    float v;
    if (j & 1) v = 0.5f * (in[j >> 1] + in[(j >> 1) + 1]);
    else       v = in[j >> 1];
    const int stride =
        (nbrs_base[1] == 0 && nbrs_base[3] == 0 && nbrs_base[5] == 0) ? 2 : 1;
    #pragma unroll
    for (int t = 0; t < 8; ++t) {
        const int idx = nbrs_base[(level * 8 + t) * stride];
        if (j == idx) v = band[t];
    }
    outf[j] = v;
}

// ---------------------------------------------------------------------------
extern "C" void kernel_launch(void* const* d_in, const int* in_sizes, int n_in,
                              void* d_out, int out_size, void* d_ws, size_t ws_size,
                              hipStream_t stream) {
    // ---- input order detection: dict (documented) / signature / alphabetical
    int iXS=0, iNB=1, iW0=4, iB0=5, iW1=6, iB1=7, iW2=8, iB2=9,
        iW3=10, iB3=11, iW4=12, iB4=13;                       // dict default
    if (n_in >= 14) {
        if (in_sizes[0] == HID) {
            iB0=0; iB1=1; iB2=2; iB3=3; iB4=4; iNB=7;
            iW0=8; iW1=9; iW2=10; iW3=11; iW4=12; iXS=13;
        } else if (!(in_sizes[1] == 40 || in_sizes[1] == 80)) {
            iXS=0; iW0=1; iB0=2; iW1=3; iB1=4; iW2=5; iB2=6;
            iW3=7; iB3=8; iW4=9; iB4=10; iNB=11;
        }
    }
    const float* xs = (const float*)d_in[iXS];
    const int* nbrs = (const int*)d_in[iNB];
    const float* w0 = (const float*)d_in[iW0];
    const float* b0 = (const float*)d_in[iB0];
    const float* w1 = (const float*)d_in[iW1];
    const float* b1 = (const float*)d_in[iB1];
    const float* w2 = (const float*)d_in[iW2];
    const float* b2 = (const float*)d_in[iB2];
    const float* w3 = (const float*)d_in[iW3];
    const float* b3 = (const float*)d_in[iB3];
    const float* w4 = (const float*)d_in[iW4];
    const float* b4 = (const float*)d_in[iB4];

    // ---- workspace layout ----
    char* ws = (char*)d_ws;
    const size_t szAmg = 66048;
    const size_t szAh1 = 524544;
    const size_t szAh2 = 1048832;
    float* Amg = (float*)(ws);
    float* ahA = (float*)(ws + szAmg);
    float* ahB = (float*)(ws + szAmg + szAh1);
    const size_t casc_end = szAmg + szAh1 + szAh2;       // 1,639,424
    const size_t szWHL  = 2ull * 3 * 1024 * BIMG * 2;    // 62,914,560 (hi+lo)
    const size_t per_tile = 2ull * 128 * HID * 4;        // 2 MB (4 bf16 act bufs)

    const int use_mfma = (ws_size >= casc_end + szWHL + per_tile) ? 1 : 0;

    unsigned short* wph = (unsigned short*)(ws + casc_end);
    unsigned short* wpl = wph + (size_t)3 * 1024 * BIMG;
    const size_t buf_start = use_mfma ? (casc_end + szWHL) : casc_end;

    size_t avail = ws_size - buf_start;
    int CT = (int)(avail / per_tile);
    if (CT < 1) CT = 1;
    if (CT > 96) CT = 96;   // 96x16=1536 blocks: exact multiple of 512 AND 768 slots

    if (use_mfma) {
        const size_t half = (size_t)CT * 128 * HID;       // shorts per act buffer
        unsigned short* bAh = (unsigned short*)(ws + buf_start);
        unsigned short* bAl = bAh + half;
        unsigned short* bBh = bAh + 2 * half;
        unsigned short* bBl = bAh + 3 * half;

        pack_w_hl<<<dim3(KTIL, NTIL, 3), 256, 0, stream>>>(w1, w2, w3, wph, wpl);

        for (int t0 = 0; t0 < MTILES; t0 += CT) {
            int tiles = (MTILES - t0 < CT) ? (MTILES - t0) : CT;
            int row0 = t0 * 128;
            layer0p<<<dim3(tiles * 128), 256, 0, stream>>>(xs, w0, b0, bAh, bAl, row0);
            dim3 ggrid(NTIL, tiles);
            gemm_hl<<<ggrid, 256, 0, stream>>>(bAh, bAl, wph, wpl, b1, bBh, bBl, 0);
            gemm_hl<<<ggrid, 256, 0, stream>>>(bBh, bBl, wph, wpl, b2, bAh, bAl, 1);
            gemm_hl<<<ggrid, 256, 0, stream>>>(bAh, bAl, wph, wpl, b3, bBh, bBl, 2);
            layer4p<<<dim3(tiles * 32), 256, 0, stream>>>(bBh, bBl, w4, b4, Amg, row0);
        }
    } else {
        float* bufA = (float*)(ws + buf_start);
        float* bufB = (float*)(ws + buf_start + (size_t)CT * 128 * HID * 4);
        for (int t0 = 0; t0 < MTILES; t0 += CT) {
            int tiles = (MTILES - t0 < CT) ? (MTILES - t0) : CT;
            int row0 = t0 * 128;
            layer0f<<<dim3(tiles * 128), 256, 0, stream>>>(xs, w0, b0, bufA, row0);
            dim3 ggrid(NTIL, tiles);
            gemm_valu<<<ggrid, 256, 0, stream>>>(bufA, w1, b1, bufB);
            gemm_valu<<<ggrid, 256, 0, stream>>>(bufB, w2, b2, bufA);
            gemm_valu<<<ggrid, 256, 0, stream>>>(bufA, w3, b3, bufB);
            layer4f<<<dim3(tiles * 32), 256, 0, stream>>>(bufB, w4, b4, Amg, row0);
        }
    }

    // multigrid cascade: 16385 -> ... -> 524289; level 4 writes d_out (fp32)
    const float* cur = Amg + 40;
    float* dsts[5] = {ahA, ahB, ahA, ahB, (float*)d_out};
    int n = 16385;
    for (int i = 0; i < 5; ++i) {
        int n_out = 2 * n - 1;
        mg_level<<<dim3((n_out + 255) / 256), 256, 0, stream>>>(
            cur, dsts[i], nbrs, i, Amg + 8 * (4 - i), n_out);
        cur = dsts[i];
        n = n_out;
    }
    (void)out_size;
}

// Round 11
// 1454.121 us; speedup vs baseline: 1.4623x; 1.4623x over previous
//
#include <hip/hip_runtime.h>
#include <stdint.h>

#define HID    2048
#define MPTS   16425
#define MTILES 129    // ceil(16425/128)
#define NTIL   16     // 2048/128
#define KTIL   64     // 2048/32
#define BIMG   5120   // shorts per packed padded B tile image (128 rows * 40)

typedef float f32x4  __attribute__((ext_vector_type(4)));
typedef short bf16x8 __attribute__((ext_vector_type(8)));

__device__ __forceinline__ float bf2f(unsigned short h) {
    unsigned u = ((unsigned)h) << 16;
    return __builtin_bit_cast(float, u);
}
__device__ __forceinline__ unsigned short f2bf(float f) {
    unsigned u = __builtin_bit_cast(unsigned, f);
    u = u + 0x7FFFu + ((u >> 16) & 1u);
    return (unsigned short)(u >> 16);
}

// P-layout (A-operand fragment order) for activations:
// elem(row local in chunk, k) -> [tile=row>>7][kt=k>>5][rowgrp=(row>>4)&7]
//                                 [quad=(k>>3)&3][lidx=row&15][j=k&7]
// linear shorts: ((tile*64+kt)<<12) + rowgrp*512 + quad*128 + lidx*8 + j
// Consumer wave A-frag load = base + lane*8 shorts  (1KB fully coalesced).

// ---------------------------------------------------------------------------
// Pack fp32 W (K x N row-major) into hi/lo bf16 padded tile images:
// img(L,nt,kt)[n*40+k] = W[kt*32+k][nt*128+n]; pad k=32..39 (zeros).
// ---------------------------------------------------------------------------
__global__ void pack_w_hl(const float* __restrict__ w1,
                          const float* __restrict__ w2,
                          const float* __restrict__ w3,
                          unsigned short* __restrict__ wph,
                          unsigned short* __restrict__ wpl) {
    const int kt = blockIdx.x, nt = blockIdx.y, L = blockIdx.z;
    const float* W = (L == 0) ? w1 : ((L == 1) ? w2 : w3);
    __shared__ float tl[128 * 33];   // [n][k] transposed, padded
    const int tid = threadIdx.x;
    const int k  = tid >> 3;          // 0..31
    const int nc = (tid & 7) * 16;    // 0..112
    const float* src = W + (size_t)(kt * 32 + k) * HID + nt * 128 + nc;
    #pragma unroll
    for (int j = 0; j < 16; ++j) tl[(nc + j) * 33 + k] = src[j];
    __syncthreads();
    const size_t base = (size_t)(L * 1024 + nt * 64 + kt) * BIMG;
    for (int e = tid; e < BIMG; e += 256) {
        int n = e / 40, kk = e - n * 40;
        float a = (kk < 32) ? tl[n * 33 + kk] : 0.f;
        unsigned short hs = f2bf(a);
        wph[base + e] = hs;
        wpl[base + e] = f2bf(a - bf2f(hs));
    }
}

// ---------------------------------------------------------------------------
// Layer 0: v=relu(xs*w0+b0); store bf16 hi/lo pair in P-layout
// ---------------------------------------------------------------------------
__global__ void layer0p(const float* __restrict__ xs,
                        const float* __restrict__ w0,
                        const float* __restrict__ b0,
                        unsigned short* __restrict__ Ahg,
                        unsigned short* __restrict__ Alg, int row0) {
    const int r = blockIdx.x;             // chunk-local row
    const int grow = row0 + r;
    const int j0 = threadIdx.x * 8;       // k
    const float x = (grow < MPTS) ? xs[grow] : 0.f;
    bf16x8 h, l;
    #pragma unroll
    for (int q = 0; q < 8; ++q) {
        float v = x * w0[j0 + q] + b0[j0 + q];
        v = v > 0.f ? v : 0.f;
        unsigned short hs = f2bf(v);
        h[q] = (short)hs;
        l[q] = (short)f2bf(v - bf2f(hs));
    }
    const int t = r >> 7, rowgrp = (r >> 4) & 7, lidx = r & 15;
    const int kt = j0 >> 5, quad = (j0 >> 3) & 3;
    const size_t dst = ((size_t)(t * 64 + kt) << 12) + rowgrp * 512 + quad * 128 + lidx * 8;
    *(bf16x8*)(Ahg + dst) = h;
    *(bf16x8*)(Alg + dst) = l;
}

// ---------------------------------------------------------------------------
// MFMA GEMM v4: A (P-layout) loaded directly from global, fully coalesced;
// B via global_load_lds into double-buffered LDS (one barrier per k-step).
// 128x128 tile, BK=32, 4 waves of 64x64, 3 MFMA per fragment pair.
// C written back in P-layout (hi/lo pair).
// ---------------------------------------------------------------------------
__launch_bounds__(256, 3)
__global__ void gemm_hl(const unsigned short* __restrict__ Ahg,
                        const unsigned short* __restrict__ Alg,
                        const unsigned short* __restrict__ wph,
                        const unsigned short* __restrict__ wpl,
                        const float* __restrict__ bias,
                        unsigned short* __restrict__ Chg,
                        unsigned short* __restrict__ Clg, int layer) {
    __shared__ short Bh[2][BIMG];   // 2 x 10240 B
    __shared__ short Bl[2][BIMG];

    const int tid  = threadIdx.x;
    const int lane = tid & 63;
    const int wave = tid >> 6;
    const int quad = lane >> 4;
    const int lidx = lane & 15;
    const int nt = blockIdx.x;
    const int mt = blockIdx.y;          // chunk-local tile
    const int mbase = (wave >> 1) * 64;
    const int nbase = (wave & 1) * 64;

    const size_t wbase = (size_t)(layer * 1024 + nt * 64) * BIMG;
    const char* gH = (const char*)(wph + wbase);
    const char* gL = (const char*)(wpl + wbase);

    // A base: P-layout frag address = abase + kt*4096 + mm*512 (+ lane*8)
    const size_t abase = ((size_t)(mt * 64) << 12) + (size_t)(mbase >> 4) * 512 + (size_t)lane * 8;
    const unsigned short* aH = Ahg + abase;
    const unsigned short* aL = Alg + abase;

    f32x4 acc[4][4];
    #pragma unroll
    for (int i = 0; i < 4; ++i)
        #pragma unroll
        for (int j = 0; j < 4; ++j) acc[i][j] = (f32x4)0.f;

    // prologue: stage kt=0 into buffer 0
    for (int t = wave; t < 10; t += 4) {
        __builtin_amdgcn_global_load_lds(
            (const __attribute__((address_space(1))) unsigned int*)(gH + t * 1024 + lane * 16),
            (__attribute__((address_space(3))) unsigned int*)((char*)&Bh[0][0] + t * 1024),
            16, 0, 0);
        __builtin_amdgcn_global_load_lds(
            (const __attribute__((address_space(1))) unsigned int*)(gL + t * 1024 + lane * 16),
            (__attribute__((address_space(3))) unsigned int*)((char*)&Bl[0][0] + t * 1024),
            16, 0, 0);
    }
    __syncthreads();

    for (int kt = 0; kt < KTIL; ++kt) {
        const int buf = kt & 1;

        // prefetch next B tile into the other buffer
        if (kt + 1 < KTIL) {
            const char* nH = gH + (size_t)(kt + 1) * (BIMG * 2);
            const char* nL = gL + (size_t)(kt + 1) * (BIMG * 2);
            char* dH = (char*)&Bh[buf ^ 1][0];
            char* dL = (char*)&Bl[buf ^ 1][0];
            for (int t = wave; t < 10; t += 4) {
                __builtin_amdgcn_global_load_lds(
                    (const __attribute__((address_space(1))) unsigned int*)(nH + t * 1024 + lane * 16),
                    (__attribute__((address_space(3))) unsigned int*)(dH + t * 1024),
                    16, 0, 0);
                __builtin_amdgcn_global_load_lds(
                    (const __attribute__((address_space(1))) unsigned int*)(nL + t * 1024 + lane * 16),
                    (__attribute__((address_space(3))) unsigned int*)(dL + t * 1024),
                    16, 0, 0);
            }
        }

        // A fragments: coalesced 1KB loads from P-layout global
        const size_t ak = (size_t)kt << 12;
        bf16x8 afh[4], afl[4];
        #pragma unroll
        for (int mm = 0; mm < 4; ++mm) {
            afh[mm] = *(const bf16x8*)(aH + ak + mm * 512);
            afl[mm] = *(const bf16x8*)(aL + ak + mm * 512);
        }

        // B fragments from LDS (current buffer)
        bf16x8 bfh[4], bfl[4];
        #pragma unroll
        for (int nn = 0; nn < 4; ++nn) {
            int r = nbase + nn * 16 + lidx;
            bfh[nn] = *(const bf16x8*)(&Bh[buf][r * 40 + quad * 8]);
            bfl[nn] = *(const bf16x8*)(&Bl[buf][r * 40 + quad * 8]);
        }

        #pragma unroll
        for (int mm = 0; mm < 4; ++mm)
            #pragma unroll
            for (int nn = 0; nn < 4; ++nn) {
                acc[mm][nn] = __builtin_amdgcn_mfma_f32_16x16x32_bf16(afh[mm], bfh[nn], acc[mm][nn], 0, 0, 0);
                acc[mm][nn] = __builtin_amdgcn_mfma_f32_16x16x32_bf16(afl[mm], bfh[nn], acc[mm][nn], 0, 0, 0);
                acc[mm][nn] = __builtin_amdgcn_mfma_f32_16x16x32_bf16(afh[mm], bfl[nn], acc[mm][nn], 0, 0, 0);
            }

        __syncthreads();   // reads of buf done; prefetch into buf^1 drained
    }

    // epilogue: C/D layout col=lane&15(row of W-out), write P-layout pair
    #pragma unroll
    for (int nn = 0; nn < 4; ++nn) {
        const int col = nt * 128 + nbase + nn * 16 + lidx;   // k of next layer
        const float bv = bias[col];
        const int kt2 = col >> 5, quad2 = (col >> 3) & 3, j2 = col & 7;
        const size_t cb = ((size_t)(mt * 64 + kt2) << 12) + quad2 * 128 + j2;
        #pragma unroll
        for (int mm = 0; mm < 4; ++mm) {
            const int rowg = (mbase >> 4) + mm;             // rowgrp
            #pragma unroll
            for (int r = 0; r < 4; ++r) {
                const int lidx2 = quad * 4 + r;             // row & 15
                float v = acc[mm][nn][r] + bv;
                v = v > 0.f ? v : 0.f;
                unsigned short hs = f2bf(v);
                const size_t idx = cb + rowg * 512 + lidx2 * 8;
                Chg[idx] = hs;
                Clg[idx] = f2bf(v - bf2f(hs));
            }
        }
    }
}

// ---------------------------------------------------------------------------
// Layer 4 (P-layout in): one block per tile; thread t: row=t&127, kt-half=t>>7
// ---------------------------------------------------------------------------
__global__ void layer4p(const unsigned short* __restrict__ Ahg,
                        const unsigned short* __restrict__ Alg,
                        const float* __restrict__ w4,
                        const float* __restrict__ b4,
                        float* __restrict__ Amg, int row0) {
    __shared__ float ps[256];
    const int mt = blockIdx.x;
    const int t = threadIdx.x;
    const int row = t & 127, half = t >> 7;
    const int rowgrp = row >> 4, lidx = row & 15;
    const size_t base = ((size_t)(mt * 64) << 12) + rowgrp * 512 + lidx * 8;
    float s = 0.f;
    for (int kt = half * 32; kt < half * 32 + 32; ++kt) {
        const unsigned short* ph = Ahg + base + ((size_t)kt << 12);
        const unsigned short* pl = Alg + base + ((size_t)kt << 12);
        const float* wv = w4 + kt * 32;
        #pragma unroll
        for (int quad = 0; quad < 4; ++quad) {
            bf16x8 hv = *(const bf16x8*)(ph + quad * 128);
            bf16x8 lv = *(const bf16x8*)(pl + quad * 128);
            #pragma unroll
            for (int j = 0; j < 8; ++j)
                s += (bf2f((unsigned short)hv[j]) + bf2f((unsigned short)lv[j])) * wv[quad * 8 + j];
        }
    }
    ps[t] = s;
    __syncthreads();
    if (t < 128) {
        const int grow = row0 + mt * 128 + t;
        if (grow < MPTS) {
            float v = ps[t] + ps[t + 128] + b4[0];
            Amg[grow] = v > 0.f ? v : 0.f;
        }
    }
}

// ---------------------------------------------------------------------------
// Fallback fp32 path (ws too small for packed images)
// ---------------------------------------------------------------------------
__global__ void layer0f(const float* __restrict__ xs, const float* __restrict__ w0,
                        const float* __restrict__ b0, float* __restrict__ A, int row0) {
    const int r = blockIdx.x;
    const int j = threadIdx.x * 8;
    const float x = (row0 + r < MPTS) ? xs[row0 + r] : 0.f;
    float* out = A + (size_t)r * HID + j;
    #pragma unroll
    for (int q = 0; q < 8; ++q) {
        float v = x * w0[j + q] + b0[j + q];
        out[q] = v > 0.f ? v : 0.f;
    }
}

__launch_bounds__(256)
__global__ void gemm_valu(const float* __restrict__ A, const float* __restrict__ W,
                          const float* __restrict__ bias, float* __restrict__ C) {
    __shared__ float As[16][132];
    __shared__ float Ws[16][132];
    const int tid = threadIdx.x;
    const int tx = tid & 15, ty = tid >> 4;
    const int n0 = blockIdx.x * 128;
    const int m0 = blockIdx.y * 128;
    const int am = tid & 127, ak = (tid >> 7) * 8;
    const int wn = (tid & 15) * 8, wk = tid >> 4;
    const float* aptr = A + (size_t)(m0 + am) * HID + ak;
    const float* wptr = W + (size_t)wk * HID + n0 + wn;
    float acc[8][8];
    #pragma unroll
    for (int i = 0; i < 8; ++i)
        #pragma unroll
        for (int j = 0; j < 8; ++j) acc[i][j] = 0.f;
    for (int k0 = 0; k0 < HID; k0 += 16) {
        f32x4 a0 = *(const f32x4*)(aptr + k0);
        f32x4 a1 = *(const f32x4*)(aptr + k0 + 4);
        f32x4 w0v = *(const f32x4*)(wptr + (size_t)k0 * HID);
        f32x4 w1v = *(const f32x4*)(wptr + (size_t)k0 * HID + 4);
        __syncthreads();
        As[ak + 0][am] = a0[0]; As[ak + 1][am] = a0[1];
        As[ak + 2][am] = a0[2]; As[ak + 3][am] = a0[3];
        As[ak + 4][am] = a1[0]; As[ak + 5][am] = a1[1];
        As[ak + 6][am] = a1[2]; As[ak + 7][am] = a1[3];
        *(f32x4*)&Ws[wk][wn]     = w0v;
        *(f32x4*)&Ws[wk][wn + 4] = w1v;
        __syncthreads();
        #pragma unroll
        for (int kk = 0; kk < 16; ++kk) {
            f32x4 av0 = *(const f32x4*)&As[kk][ty * 8];
            f32x4 av1 = *(const f32x4*)&As[kk][ty * 8 + 4];
            f32x4 bv0 = *(const f32x4*)&Ws[kk][tx * 8];
            f32x4 bv1 = *(const f32x4*)&Ws[kk][tx * 8 + 4];
            float a[8] = {av0[0], av0[1], av0[2], av0[3], av1[0], av1[1], av1[2], av1[3]};
            float b[8] = {bv0[0], bv0[1], bv0[2], bv0[3], bv1[0], bv1[1], bv1[2], bv1[3]};
            #pragma unroll
            for (int i = 0; i < 8; ++i)
                #pragma unroll
                for (int j = 0; j < 8; ++j) acc[i][j] += a[i] * b[j];
        }
    }
    #pragma unroll
    for (int i = 0; i < 8; ++i) {
        const int m = m0 + ty * 8 + i;
        #pragma unroll
        for (int jc = 0; jc < 2; ++jc) {
            const int n = n0 + tx * 8 + jc * 4;
            f32x4 v4;
            #pragma unroll
            for (int q = 0; q < 4; ++q) {
                float v = acc[i][jc * 4 + q] + bias[n + q];
                v4[q] = v > 0.f ? v : 0.f;
            }
            *(f32x4*)(C + (size_t)m * HID + n) = v4;
        }
    }
}

__global__ void layer4f(const float* __restrict__ A, const float* __restrict__ w4,
                        const float* __restrict__ b4, float* __restrict__ Amg, int row0) {
    const int lane = threadIdx.x & 63;
    const int wave = threadIdx.x >> 6;
    const int r    = blockIdx.x * 4 + wave;
    if (row0 + r >= MPTS) return;
    const float* ap = A + (size_t)r * HID;
    float s = 0.f;
    #pragma unroll
    for (int c = 0; c < 8; ++c) {
        const int col = c * 256 + lane * 4;
        f32x4 av = *(const f32x4*)(ap + col);
        f32x4 wv = *(const f32x4*)(w4 + col);
        s += av[0] * wv[0] + av[1] * wv[1] + av[2] * wv[2] + av[3] * wv[3];
    }
    #pragma unroll
    for (int off = 32; off; off >>= 1) s += __shfl_down(s, off);
    if (lane == 0) {
        float v = s + b4[0];
        Amg[row0 + r] = v > 0.f ? v : 0.f;
    }
}

// ---------------------------------------------------------------------------
// Multigrid level: interp (2n-1) + band overwrite; all fp32 (d_out is fp32).
// ---------------------------------------------------------------------------
__global__ void mg_level(const float* __restrict__ in, float* __restrict__ outf,
                         const int* __restrict__ nbrs_base, int level,
                         const float* __restrict__ band, int n_out) {
    const int j = blockIdx.x * 256 + threadIdx.x;
    if (j >= n_out) return;
    float v;
    if (j & 1) v = 0.5f * (in[j >> 1] + in[(j >> 1) + 1]);
    else       v = in[j >> 1];
    const int stride =
        (nbrs_base[1] == 0 && nbrs_base[3] == 0 && nbrs_base[5] == 0) ? 2 : 1;
    #pragma unroll
    for (int t = 0; t < 8; ++t) {
        const int idx = nbrs_base[(level * 8 + t) * stride];
        if (j == idx) v = band[t];
    }
    outf[j] = v;
}

// ---------------------------------------------------------------------------
extern "C" void kernel_launch(void* const* d_in, const int* in_sizes, int n_in,
                              void* d_out, int out_size, void* d_ws, size_t ws_size,
                              hipStream_t stream) {
    // ---- input order detection: dict (documented) / signature / alphabetical
    int iXS=0, iNB=1, iW0=4, iB0=5, iW1=6, iB1=7, iW2=8, iB2=9,
        iW3=10, iB3=11, iW4=12, iB4=13;                       // dict default
    if (n_in >= 14) {
        if (in_sizes[0] == HID) {
            iB0=0; iB1=1; iB2=2; iB3=3; iB4=4; iNB=7;
            iW0=8; iW1=9; iW2=10; iW3=11; iW4=12; iXS=13;
        } else if (!(in_sizes[1] == 40 || in_sizes[1] == 80)) {
            iXS=0; iW0=1; iB0=2; iW1=3; iB1=4; iW2=5; iB2=6;
            iW3=7; iB3=8; iW4=9; iB4=10; iNB=11;
        }
    }
    const float* xs = (const float*)d_in[iXS];
    const int* nbrs = (const int*)d_in[iNB];
    const float* w0 = (const float*)d_in[iW0];
    const float* b0 = (const float*)d_in[iB0];
    const float* w1 = (const float*)d_in[iW1];
    const float* b1 = (const float*)d_in[iB1];
    const float* w2 = (const float*)d_in[iW2];
    const float* b2 = (const float*)d_in[iB2];
    const float* w3 = (const float*)d_in[iW3];
    const float* b3 = (const float*)d_in[iB3];
    const float* w4 = (const float*)d_in[iW4];
    const float* b4 = (const float*)d_in[iB4];

    // ---- workspace layout ----
    char* ws = (char*)d_ws;
    const size_t szAmg = 66048;
    const size_t szAh1 = 524544;
    const size_t szAh2 = 1048832;
    float* Amg = (float*)(ws);
    float* ahA = (float*)(ws + szAmg);
    float* ahB = (float*)(ws + szAmg + szAh1);
    const size_t casc_end = szAmg + szAh1 + szAh2;       // 1,639,424
    const size_t szWHL  = 2ull * 3 * 1024 * BIMG * 2;    // 62,914,560 (hi+lo)
    const size_t per_tile = 2ull * 128 * HID * 4;        // 2 MB (4 bf16 act bufs)

    const int use_mfma = (ws_size >= casc_end + szWHL + per_tile) ? 1 : 0;

    unsigned short* wph = (unsigned short*)(ws + casc_end);
    unsigned short* wpl = wph + (size_t)3 * 1024 * BIMG;
    const size_t buf_start = use_mfma ? (casc_end + szWHL) : casc_end;

    size_t avail = ws_size - buf_start;
    int CT = (int)(avail / per_tile);
    if (CT < 1) CT = 1;
    if (CT > 96) CT = 96;   // 96x16=1536 blocks

    if (use_mfma) {
        const size_t half = (size_t)CT * 128 * HID;       // shorts per act buffer
        unsigned short* bAh = (unsigned short*)(ws + buf_start);
        unsigned short* bAl = bAh + half;
        unsigned short* bBh = bAh + 2 * half;
        unsigned short* bBl = bAh + 3 * half;

        pack_w_hl<<<dim3(KTIL, NTIL, 3), 256, 0, stream>>>(w1, w2, w3, wph, wpl);

        for (int t0 = 0; t0 < MTILES; t0 += CT) {
            int tiles = (MTILES - t0 < CT) ? (MTILES - t0) : CT;
            int row0 = t0 * 128;
            layer0p<<<dim3(tiles * 128), 256, 0, stream>>>(xs, w0, b0, bAh, bAl, row0);
            dim3 ggrid(NTIL, tiles);
            gemm_hl<<<ggrid, 256, 0, stream>>>(bAh, bAl, wph, wpl, b1, bBh, bBl, 0);
            gemm_hl<<<ggrid, 256, 0, stream>>>(bBh, bBl, wph, wpl, b2, bAh, bAl, 1);
            gemm_hl<<<ggrid, 256, 0, stream>>>(bAh, bAl, wph, wpl, b3, bBh, bBl, 2);
            layer4p<<<dim3(tiles), 256, 0, stream>>>(bBh, bBl, w4, b4, Amg, row0);
        }
    } else {
        float* bufA = (float*)(ws + buf_start);
        float* bufB = (float*)(ws + buf_start + (size_t)CT * 128 * HID * 4);
        for (int t0 = 0; t0 < MTILES; t0 += CT) {
            int tiles = (MTILES - t0 < CT) ? (MTILES - t0) : CT;
            int row0 = t0 * 128;
            layer0f<<<dim3(tiles * 128), 256, 0, stream>>>(xs, w0, b0, bufA, row0);
            dim3 ggrid(NTIL, tiles);
            gemm_valu<<<ggrid, 256, 0, stream>>>(bufA, w1, b1, bufB);
            gemm_valu<<<ggrid, 256, 0, stream>>>(bufB, w2, b2, bufA);
            gemm_valu<<<ggrid, 256, 0, stream>>>(bufA, w3, b3, bufB);
            layer4f<<<dim3(tiles * 32), 256, 0, stream>>>(bufB, w4, b4, Amg, row0);
        }
    }

    // multigrid cascade: 16385 -> ... -> 524289; level 4 writes d_out (fp32)
    const float* cur = Amg + 40;
    float* dsts[5] = {ahA, ahB, ahA, ahB, (float*)d_out};
    int n = 16385;
    for (int i = 0; i < 5; ++i) {
        int n_out = 2 * n - 1;
        mg_level<<<dim3((n_out + 255) / 256), 256, 0, stream>>>(
            cur, dsts[i], nbrs, i, Amg + 8 * (4 - i), n_out);
        cur = dsts[i];
        n = n_out;
    }
    (void)out_size;
}

// Round 12
// 1213.759 us; speedup vs baseline: 1.7519x; 1.1980x over previous
//
#include <hip/hip_runtime.h>
#include <stdint.h>

#define HID    2048
#define MPTS   16425
#define MTILES 129    // ceil(16425/128)
#define NTIL   16     // 2048/128
#define KTIL   64     // 2048/32
#define BIMG   5120   // f16 elems per packed padded B tile image (128 rows * 40)

typedef float    f32x4 __attribute__((ext_vector_type(4)));
typedef _Float16 f16x8 __attribute__((ext_vector_type(8)));

// P-layout (A-operand fragment order) for activations:
// elem(row, k) -> linear ((tile*64+kt)<<12) + rowgrp*512 + quad*128 + lidx*8 + j
//   tile=row>>7, rowgrp=(row>>4)&7, lidx=row&15, kt=k>>5, quad=(k>>3)&3, j=k&7
// Consumer wave A-frag load = base + lane*8 halves (1KB fully coalesced).

// ---------------------------------------------------------------------------
// Pack fp32 W (K x N row-major) into single-fp16 padded tile images:
// img(L,nt,kt)[n*40+k] = (f16)W[kt*32+k][nt*128+n]; pad k=32..39 zeros.
// ---------------------------------------------------------------------------
__global__ void pack_w16(const float* __restrict__ w1,
                         const float* __restrict__ w2,
                         const float* __restrict__ w3,
                         _Float16* __restrict__ wp) {
    const int kt = blockIdx.x, nt = blockIdx.y, L = blockIdx.z;
    const float* W = (L == 0) ? w1 : ((L == 1) ? w2 : w3);
    __shared__ float tl[128 * 33];   // [n][k] transposed, padded
    const int tid = threadIdx.x;
    const int k  = tid >> 3;          // 0..31
    const int nc = (tid & 7) * 16;    // 0..112
    const float* src = W + (size_t)(kt * 32 + k) * HID + nt * 128 + nc;
    #pragma unroll
    for (int j = 0; j < 16; ++j) tl[(nc + j) * 33 + k] = src[j];
    __syncthreads();
    const size_t base = (size_t)(L * 1024 + nt * 64 + kt) * BIMG;
    for (int e = tid; e < BIMG; e += 256) {
        int n = e / 40, kk = e - n * 40;
        wp[base + e] = (kk < 32) ? (_Float16)tl[n * 33 + kk] : (_Float16)0.f;
    }
}

// ---------------------------------------------------------------------------
// Layer 0: v=relu(xs*w0+b0); store fp16 hi/lo pair in P-layout
// ---------------------------------------------------------------------------
__global__ void layer0p(const float* __restrict__ xs,
                        const float* __restrict__ w0,
                        const float* __restrict__ b0,
                        _Float16* __restrict__ Ahg,
                        _Float16* __restrict__ Alg, int row0) {
    const int r = blockIdx.x;             // chunk-local row
    const int grow = row0 + r;
    const int j0 = threadIdx.x * 8;       // k
    const float x = (grow < MPTS) ? xs[grow] : 0.f;
    f16x8 h, l;
    #pragma unroll
    for (int q = 0; q < 8; ++q) {
        float v = x * w0[j0 + q] + b0[j0 + q];
        v = v > 0.f ? v : 0.f;
        _Float16 hs = (_Float16)v;
        h[q] = hs;
        l[q] = (_Float16)(v - (float)hs);
    }
    const int t = r >> 7, rowgrp = (r >> 4) & 7, lidx = r & 15;
    const int kt = j0 >> 5, quad = (j0 >> 3) & 3;
    const size_t dst = ((size_t)(t * 64 + kt) << 12) + rowgrp * 512 + quad * 128 + lidx * 8;
    *(f16x8*)(Ahg + dst) = h;
    *(f16x8*)(Alg + dst) = l;
}

// ---------------------------------------------------------------------------
// MFMA GEMM v5 (fp16): A (P-layout hi/lo) direct from global, coalesced;
// W single-fp16 image via global_load_lds, double-buffered (1 barrier/kt).
// 128x128 tile, BK=32, 4 waves of 64x64, 2 MFMA per fragment pair:
// acc += Ah*W; acc += Al*W  (A carries 22 mantissa bits; W 11).
// C written in P-layout; lo plane skipped when write_lo==0 (last layer).
// ---------------------------------------------------------------------------
__launch_bounds__(256, 3)
__global__ void gemm_hl(const _Float16* __restrict__ Ahg,
                        const _Float16* __restrict__ Alg,
                        const _Float16* __restrict__ wp,
                        const float* __restrict__ bias,
                        _Float16* __restrict__ Chg,
                        _Float16* __restrict__ Clg,
                        int layer, int write_lo) {
    __shared__ _Float16 Bs[2][BIMG];   // 2 x 10240 B

    const int tid  = threadIdx.x;
    const int lane = tid & 63;
    const int wave = tid >> 6;
    const int quad = lane >> 4;
    const int lidx = lane & 15;
    const int nt = blockIdx.x;
    const int mt = blockIdx.y;          // chunk-local tile
    const int mbase = (wave >> 1) * 64;
    const int nbase = (wave & 1) * 64;

    const char* gW = (const char*)(wp + (size_t)(layer * 1024 + nt * 64) * BIMG);

    const size_t abase = ((size_t)(mt * 64) << 12) + (size_t)(mbase >> 4) * 512 + (size_t)lane * 8;
    const _Float16* aH = Ahg + abase;
    const _Float16* aL = Alg + abase;

    f32x4 acc[4][4];
    #pragma unroll
    for (int i = 0; i < 4; ++i)
        #pragma unroll
        for (int j = 0; j < 4; ++j) acc[i][j] = (f32x4)0.f;

    // prologue: stage kt=0 into buffer 0
    for (int t = wave; t < 10; t += 4) {
        __builtin_amdgcn_global_load_lds(
            (const __attribute__((address_space(1))) unsigned int*)(gW + t * 1024 + lane * 16),
            (__attribute__((address_space(3))) unsigned int*)((char*)&Bs[0][0] + t * 1024),
            16, 0, 0);
    }
    __syncthreads();

    for (int kt = 0; kt < KTIL; ++kt) {
        const int buf = kt & 1;

        // prefetch next B tile into the other buffer (in flight across MFMA)
        if (kt + 1 < KTIL) {
            const char* nW = gW + (size_t)(kt + 1) * (BIMG * 2);
            char* dW = (char*)&Bs[buf ^ 1][0];
            for (int t = wave; t < 10; t += 4) {
                __builtin_amdgcn_global_load_lds(
                    (const __attribute__((address_space(1))) unsigned int*)(nW + t * 1024 + lane * 16),
                    (__attribute__((address_space(3))) unsigned int*)(dW + t * 1024),
                    16, 0, 0);
            }
        }

        // A fragments: coalesced 1KB loads from P-layout global
        const size_t ak = (size_t)kt << 12;
        f16x8 afh[4], afl[4];
        #pragma unroll
        for (int mm = 0; mm < 4; ++mm) {
            afh[mm] = *(const f16x8*)(aH + ak + mm * 512);
            afl[mm] = *(const f16x8*)(aL + ak + mm * 512);
        }

        // B fragments from LDS (current buffer)
        f16x8 bfr[4];
        #pragma unroll
        for (int nn = 0; nn < 4; ++nn) {
            int r = nbase + nn * 16 + lidx;
            bfr[nn] = *(const f16x8*)(&Bs[buf][r * 40 + quad * 8]);
        }

        #pragma unroll
        for (int mm = 0; mm < 4; ++mm)
            #pragma unroll
            for (int nn = 0; nn < 4; ++nn) {
                acc[mm][nn] = __builtin_amdgcn_mfma_f32_16x16x32_f16(afh[mm], bfr[nn], acc[mm][nn], 0, 0, 0);
                acc[mm][nn] = __builtin_amdgcn_mfma_f32_16x16x32_f16(afl[mm], bfr[nn], acc[mm][nn], 0, 0, 0);
            }

        __syncthreads();   // reads of buf done; prefetch into buf^1 drained
    }

    // epilogue: C/D layout col=lane&15, row=quad*4+reg; write P-layout pair
    #pragma unroll
    for (int nn = 0; nn < 4; ++nn) {
        const int col = nt * 128 + nbase + nn * 16 + lidx;   // k of next layer
        const float bv = bias[col];
        const int kt2 = col >> 5, quad2 = (col >> 3) & 3, j2 = col & 7;
        const size_t cb = ((size_t)(mt * 64 + kt2) << 12) + quad2 * 128 + j2;
        #pragma unroll
        for (int mm = 0; mm < 4; ++mm) {
            const int rowg = (mbase >> 4) + mm;             // rowgrp
            #pragma unroll
            for (int r = 0; r < 4; ++r) {
                const int lidx2 = quad * 4 + r;             // row & 15
                float v = acc[mm][nn][r] + bv;
                v = v > 0.f ? v : 0.f;
                _Float16 hs = (_Float16)v;
                const size_t idx = cb + rowg * 512 + lidx2 * 8;
                Chg[idx] = hs;
                if (write_lo) Clg[idx] = (_Float16)(v - (float)hs);
            }
        }
    }
}

// ---------------------------------------------------------------------------
// Layer 4 (P-layout hi only): one block per tile; t: row=t&127, half=t>>7
// ---------------------------------------------------------------------------
__global__ void layer4p(const _Float16* __restrict__ Ahg,
                        const float* __restrict__ w4,
                        const float* __restrict__ b4,
                        float* __restrict__ Amg, int row0) {
    __shared__ float ps[256];
    const int mt = blockIdx.x;
    const int t = threadIdx.x;
    const int row = t & 127, half = t >> 7;
    const int rowgrp = row >> 4, lidx = row & 15;
    const size_t base = ((size_t)(mt * 64) << 12) + rowgrp * 512 + lidx * 8;
    float s = 0.f;
    for (int kt = half * 32; kt < half * 32 + 32; ++kt) {
        const _Float16* ph = Ahg + base + ((size_t)kt << 12);
        const float* wv = w4 + kt * 32;
        #pragma unroll
        for (int quad = 0; quad < 4; ++quad) {
            f16x8 hv = *(const f16x8*)(ph + quad * 128);
            #pragma unroll
            for (int j = 0; j < 8; ++j)
                s += (float)hv[j] * wv[quad * 8 + j];
        }
    }
    ps[t] = s;
    __syncthreads();
    if (t < 128) {
        const int grow = row0 + mt * 128 + t;
        if (grow < MPTS) {
            float v = ps[t] + ps[t + 128] + b4[0];
            Amg[grow] = v > 0.f ? v : 0.f;
        }
    }
}

// ---------------------------------------------------------------------------
// Fallback fp32 path (ws too small for packed images)
// ---------------------------------------------------------------------------
__global__ void layer0f(const float* __restrict__ xs, const float* __restrict__ w0,
                        const float* __restrict__ b0, float* __restrict__ A, int row0) {
    const int r = blockIdx.x;
    const int j = threadIdx.x * 8;
    const float x = (row0 + r < MPTS) ? xs[row0 + r] : 0.f;
    float* out = A + (size_t)r * HID + j;
    #pragma unroll
    for (int q = 0; q < 8; ++q) {
        float v = x * w0[j + q] + b0[j + q];
        out[q] = v > 0.f ? v : 0.f;
    }
}

__launch_bounds__(256)
__global__ void gemm_valu(const float* __restrict__ A, const float* __restrict__ W,
                          const float* __restrict__ bias, float* __restrict__ C) {
    __shared__ float As[16][132];
    __shared__ float Ws[16][132];
    const int tid = threadIdx.x;
    const int tx = tid & 15, ty = tid >> 4;
    const int n0 = blockIdx.x * 128;
    const int m0 = blockIdx.y * 128;
    const int am = tid & 127, ak = (tid >> 7) * 8;
    const int wn = (tid & 15) * 8, wk = tid >> 4;
    const float* aptr = A + (size_t)(m0 + am) * HID + ak;
    const float* wptr = W + (size_t)wk * HID + n0 + wn;
    float acc[8][8];
    #pragma unroll
    for (int i = 0; i < 8; ++i)
        #pragma unroll
        for (int j = 0; j < 8; ++j) acc[i][j] = 0.f;
    for (int k0 = 0; k0 < HID; k0 += 16) {
        f32x4 a0 = *(const f32x4*)(aptr + k0);
        f32x4 a1 = *(const f32x4*)(aptr + k0 + 4);
        f32x4 w0v = *(const f32x4*)(wptr + (size_t)k0 * HID);
        f32x4 w1v = *(const f32x4*)(wptr + (size_t)k0 * HID + 4);
        __syncthreads();
        As[ak + 0][am] = a0[0]; As[ak + 1][am] = a0[1];
        As[ak + 2][am] = a0[2]; As[ak + 3][am] = a0[3];
        As[ak + 4][am] = a1[0]; As[ak + 5][am] = a1[1];
        As[ak + 6][am] = a1[2]; As[ak + 7][am] = a1[3];
        *(f32x4*)&Ws[wk][wn]     = w0v;
        *(f32x4*)&Ws[wk][wn + 4] = w1v;
        __syncthreads();
        #pragma unroll
        for (int kk = 0; kk < 16; ++kk) {
            f32x4 av0 = *(const f32x4*)&As[kk][ty * 8];
            f32x4 av1 = *(const f32x4*)&As[kk][ty * 8 + 4];
            f32x4 bv0 = *(const f32x4*)&Ws[kk][tx * 8];
            f32x4 bv1 = *(const f32x4*)&Ws[kk][tx * 8 + 4];
            float a[8] = {av0[0], av0[1], av0[2], av0[3], av1[0], av1[1], av1[2], av1[3]};
            float b[8] = {bv0[0], bv0[1], bv0[2], bv0[3], bv1[0], bv1[1], bv1[2], bv1[3]};
            #pragma unroll
            for (int i = 0; i < 8; ++i)
                #pragma unroll
                for (int j = 0; j < 8; ++j) acc[i][j] += a[i] * b[j];
        }
    }
    #pragma unroll
    for (int i = 0; i < 8; ++i) {
        const int m = m0 + ty * 8 + i;
        #pragma unroll
        for (int jc = 0; jc < 2; ++jc) {
            const int n = n0 + tx * 8 + jc * 4;
            f32x4 v4;
            #pragma unroll
            for (int q = 0; q < 4; ++q) {
                float v = acc[i][jc * 4 + q] + bias[n + q];
                v4[q] = v > 0.f ? v : 0.f;
            }
            *(f32x4*)(C + (size_t)m * HID + n) = v4;
        }
    }
}

__global__ void layer4f(const float* __restrict__ A, const float* __restrict__ w4,
                        const float* __restrict__ b4, float* __restrict__ Amg, int row0) {
    const int lane = threadIdx.x & 63;
    const int wave = threadIdx.x >> 6;
    const int r    = blockIdx.x * 4 + wave;
    if (row0 + r >= MPTS) return;
    const float* ap = A + (size_t)r * HID;
    float s = 0.f;
    #pragma unroll
    for (int c = 0; c < 8; ++c) {
        const int col = c * 256 + lane * 4;
        f32x4 av = *(const f32x4*)(ap + col);
        f32x4 wv = *(const f32x4*)(w4 + col);
        s += av[0] * wv[0] + av[1] * wv[1] + av[2] * wv[2] + av[3] * wv[3];
    }
    #pragma unroll
    for (int off = 32; off; off >>= 1) s += __shfl_down(s, off);
    if (lane == 0) {
        float v = s + b4[0];
        Amg[row0 + r] = v > 0.f ? v : 0.f;
    }
}

// ---------------------------------------------------------------------------
// Multigrid level: interp (2n-1) + band overwrite; all fp32 (d_out is fp32).
// ---------------------------------------------------------------------------
__global__ void mg_level(const float* __restrict__ in, float* __restrict__ outf,
                         const int* __restrict__ nbrs_base, int level,
                         const float* __restrict__ band, int n_out) {
    const int j = blockIdx.x * 256 + threadIdx.x;
    if (j >= n_out) return;
    float v;
    if (j & 1) v = 0.5f * (in[j >> 1] + in[(j >> 1) + 1]);
    else       v = in[j >> 1];
    const int stride =
        (nbrs_base[1] == 0 && nbrs_base[3] == 0 && nbrs_base[5] == 0) ? 2 : 1;
    #pragma unroll
    for (int t = 0; t < 8; ++t) {
        const int idx = nbrs_base[(level * 8 + t) * stride];
        if (j == idx) v = band[t];
    }
    outf[j] = v;
}

// ---------------------------------------------------------------------------
extern "C" void kernel_launch(void* const* d_in, const int* in_sizes, int n_in,
                              void* d_out, int out_size, void* d_ws, size_t ws_size,
                              hipStream_t stream) {
    // ---- input order detection: dict (documented) / signature / alphabetical
    int iXS=0, iNB=1, iW0=4, iB0=5, iW1=6, iB1=7, iW2=8, iB2=9,
        iW3=10, iB3=11, iW4=12, iB4=13;                       // dict default
    if (n_in >= 14) {
        if (in_sizes[0] == HID) {
            iB0=0; iB1=1; iB2=2; iB3=3; iB4=4; iNB=7;
            iW0=8; iW1=9; iW2=10; iW3=11; iW4=12; iXS=13;
        } else if (!(in_sizes[1] == 40 || in_sizes[1] == 80)) {
            iXS=0; iW0=1; iB0=2; iW1=3; iB1=4; iW2=5; iB2=6;
            iW3=7; iB3=8; iW4=9; iB4=10; iNB=11;
        }
    }
    const float* xs = (const float*)d_in[iXS];
    const int* nbrs = (const int*)d_in[iNB];
    const float* w0 = (const float*)d_in[iW0];
    const float* b0 = (const float*)d_in[iB0];
    const float* w1 = (const float*)d_in[iW1];
    const float* b1 = (const float*)d_in[iB1];
    const float* w2 = (const float*)d_in[iW2];
    const float* b2 = (const float*)d_in[iB2];
    const float* w3 = (const float*)d_in[iW3];
    const float* b3 = (const float*)d_in[iB3];
    const float* w4 = (const float*)d_in[iW4];
    const float* b4 = (const float*)d_in[iB4];

    // ---- workspace layout ----
    char* ws = (char*)d_ws;
    const size_t szAmg = 66048;
    const size_t szAh1 = 524544;
    const size_t szAh2 = 1048832;
    float* Amg = (float*)(ws);
    float* ahA = (float*)(ws + szAmg);
    float* ahB = (float*)(ws + szAmg + szAh1);
    const size_t casc_end = szAmg + szAh1 + szAh2;       // 1,639,424
    const size_t szW    = (size_t)3 * 1024 * BIMG * 2;   // 31,457,280 (fp16)
    const size_t per_tile = 2ull * 128 * HID * 4;        // 2 MB (4 fp16 act bufs)

    const int use_mfma = (ws_size >= casc_end + szW + per_tile) ? 1 : 0;

    _Float16* wp = (_Float16*)(ws + casc_end);
    const size_t buf_start = use_mfma ? (casc_end + szW) : casc_end;

    size_t avail = ws_size - buf_start;
    int CT = (int)(avail / per_tile);
    if (CT < 1) CT = 1;
    if (CT > 96) CT = 96;   // 96x16=1536 blocks: 2 exact rounds at 3 blk/CU

    if (use_mfma) {
        const size_t half = (size_t)CT * 128 * HID;       // f16 elems per buffer
        _Float16* bAh = (_Float16*)(ws + buf_start);
        _Float16* bAl = bAh + half;
        _Float16* bBh = bAh + 2 * half;
        _Float16* bBl = bAh + 3 * half;

        pack_w16<<<dim3(KTIL, NTIL, 3), 256, 0, stream>>>(w1, w2, w3, wp);

        for (int t0 = 0; t0 < MTILES; t0 += CT) {
            int tiles = (MTILES - t0 < CT) ? (MTILES - t0) : CT;
            int row0 = t0 * 128;
            layer0p<<<dim3(tiles * 128), 256, 0, stream>>>(xs, w0, b0, bAh, bAl, row0);
            dim3 ggrid(NTIL, tiles);
            gemm_hl<<<ggrid, 256, 0, stream>>>(bAh, bAl, wp, b1, bBh, bBl, 0, 1);
            gemm_hl<<<ggrid, 256, 0, stream>>>(bBh, bBl, wp, b2, bAh, bAl, 1, 1);
            gemm_hl<<<ggrid, 256, 0, stream>>>(bAh, bAl, wp, b3, bBh, bBl, 2, 0);
            layer4p<<<dim3(tiles), 256, 0, stream>>>(bBh, w4, b4, Amg, row0);
        }
    } else {
        float* bufA = (float*)(ws + buf_start);
        float* bufB = (float*)(ws + buf_start + (size_t)CT * 128 * HID * 4);
        for (int t0 = 0; t0 < MTILES; t0 += CT) {
            int tiles = (MTILES - t0 < CT) ? (MTILES - t0) : CT;
            int row0 = t0 * 128;
            layer0f<<<dim3(tiles * 128), 256, 0, stream>>>(xs, w0, b0, bufA, row0);
            dim3 ggrid(NTIL, tiles);
            gemm_valu<<<ggrid, 256, 0, stream>>>(bufA, w1, b1, bufB);
            gemm_valu<<<ggrid, 256, 0, stream>>>(bufB, w2, b2, bufA);
            gemm_valu<<<ggrid, 256, 0, stream>>>(bufA, w3, b3, bufB);
            layer4f<<<dim3(tiles * 32), 256, 0, stream>>>(bufB, w4, b4, Amg, row0);
        }
    }

    // multigrid cascade: 16385 -> ... -> 524289; level 4 writes d_out (fp32)
    const float* cur = Amg + 40;
    float* dsts[5] = {ahA, ahB, ahA, ahB, (float*)d_out};
    int n = 16385;
    for (int i = 0; i < 5; ++i) {
        int n_out = 2 * n - 1;
        mg_level<<<dim3((n_out + 255) / 256), 256, 0, stream>>>(
            cur, dsts[i], nbrs, i, Amg + 8 * (4 - i), n_out);
        cur = dsts[i];
        n = n_out;
    }
    (void)out_size;
}